// Round 5
// baseline (100.040 us; speedup 1.0000x reference)
//
#include <hip/hip_runtime.h>
#include <hip/hip_bf16.h>
#include <math.h>

#define NSLICES 1024
#define DIM     768
#define NPTS    256
#define K_REF   17
#define KSPLIT  8
#define KCHUNK  (DIM / KSPLIT)      // 96
#define XSZ     (NSLICES * NPTS)    // 262144 floats per (z, kchunk) partial
#define PITCH   132                 // LDS row pitch: 2-way (free) bank aliasing both sides

// ws float layout — every slot is fully rewritten every call (no zero-init needed)
#define INV_OFF 0                   // 192 partials
#define G_OFF   208                 // 17 scaled reference points
#define SIG_OFF 256                 // 2048 partials
#define XP_OFF  2560                // projection partials

#define EXP2(x) __builtin_amdgcn_exp2f(x)
// y = x * SCALE_A  =>  exp(-0.5(xi-xj)^2) == exp2(-(yi-yj)^2)
#define SCALE_A 0.84932180028801904272f      // sqrt(0.5 * log2(e))
#define INV_N2  1.52587890625e-05f           // 1/256^2
#define T2_SC   4.595588235294118e-4f        // 2/(256*17)

__device__ __forceinline__ float wave_sum(float v) {
#pragma unroll
    for (int o = 32; o; o >>= 1) v += __shfl_xor(v, o, 64);
    return v;
}

__device__ __forceinline__ float block_sum_256(float v, float* wred, int tid) {
    v = wave_sum(v);
    if ((tid & 63) == 0) wred[tid >> 6] = v;
    __syncthreads();
    float r = wred[0] + wred[1] + wred[2] + wred[3];
    __syncthreads();
    return r;
}

// ---------------- inv_loss partials + scaled reference points ---------------
__global__ __launch_bounds__(256) void inv_kernel(const float* __restrict__ za,
                                                  const float* __restrict__ zb,
                                                  float* __restrict__ w) {
    __shared__ float wred[4];
    int tid = threadIdx.x;
    int idx = blockIdx.x * 256 + tid;           // 192 blocks * 256 = 49152 float4s exactly
    const float4* A = (const float4*)za;
    const float4* B = (const float4*)zb;
    float4 a = A[idx], b = B[idx];
    float dx = a.x - b.x, dy = a.y - b.y, dz = a.z - b.z, dw = a.w - b.w;
    float p = dx * dx + dy * dy + dz * dz + dw * dw;
    float s = block_sum_256(p, wred, tid);
    if (tid == 0) w[INV_OFF + blockIdx.x] = s;
    if (blockIdx.x == 0 && tid < K_REF) {
        float q = 0.01f + 0.06125f * (float)tid;
        w[G_OFF + tid] = erfinvf(2.0f * q - 1.0f) * 1.41421356237309504880f * SCALE_A;
    }
}

// ---------------- projection GEMM: x[m][n] = dot(slices[m], z[n]) -----------
// (slice normalization dropped: standardization is scale-invariant per slice)
// Tile 128(m) x 128(n), block 256 = 16x16, 8x(4+4) outputs/thread (1 B/FMA LDS).
// grid: (2 n-tiles, 8 m-tiles, 2 z * KSPLIT k-chunks) = 256 blocks (1/CU).
// k-major coalesced global loads; transposed LDS [k][row], pitch 132 (2-way=free).
// Reg-staged double buffer hides global latency at 1 block/CU.
__global__ __launch_bounds__(256) void proj_kernel(const float* __restrict__ za,
                                                   const float* __restrict__ zb,
                                                   const float* __restrict__ slices,
                                                   float* __restrict__ w, int npart) {
    __shared__ float sA[16][PITCH];
    __shared__ float sB[16][PITCH];
    const int nt = blockIdx.x;            // 0..1
    const int mt = blockIdx.y;            // 0..7
    const int zi = blockIdx.z >> 3;       // 0..1
    const int kc = blockIdx.z & 7;        // 0..7
    const float* Z = zi ? zb : za;
    const int m0 = mt * 128, n0 = nt * 128;
    const int tid = threadIdx.x;
    const int tx = tid & 15, ty = tid >> 4;
    const int lk = (tid & 3) * 4;         // k-offset of this thread's float4
    const int lr = tid >> 2;              // row 0..63 (second batch: +64)
    const int kbase = kc * KCHUNK;

    const float* A0 = slices + (size_t)(m0 + lr) * DIM + kbase + lk;
    const float* A1 = slices + (size_t)(m0 + 64 + lr) * DIM + kbase + lk;
    const float* B0 = Z + (size_t)(n0 + lr) * DIM + kbase + lk;
    const float* B1 = Z + (size_t)(n0 + 64 + lr) * DIM + kbase + lk;

    float acc0[8][4] = {};
    float acc1[8][4] = {};
    float4 ra0, ra1, rb0, rb1;

#define LOAD_STAGE(off) do { \
    ra0 = *(const float4*)(A0 + (off)); ra1 = *(const float4*)(A1 + (off)); \
    rb0 = *(const float4*)(B0 + (off)); rb1 = *(const float4*)(B1 + (off)); } while (0)

#define STORE_STAGE() do { \
    sA[lk + 0][lr] = ra0.x; sA[lk + 1][lr] = ra0.y; sA[lk + 2][lr] = ra0.z; sA[lk + 3][lr] = ra0.w; \
    sA[lk + 0][64 + lr] = ra1.x; sA[lk + 1][64 + lr] = ra1.y; sA[lk + 2][64 + lr] = ra1.z; sA[lk + 3][64 + lr] = ra1.w; \
    sB[lk + 0][lr] = rb0.x; sB[lk + 1][lr] = rb0.y; sB[lk + 2][lr] = rb0.z; sB[lk + 3][lr] = rb0.w; \
    sB[lk + 0][64 + lr] = rb1.x; sB[lk + 1][64 + lr] = rb1.y; sB[lk + 2][64 + lr] = rb1.z; sB[lk + 3][64 + lr] = rb1.w; } while (0)

    LOAD_STAGE(0);
    STORE_STAGE();
    __syncthreads();

    for (int s = 0; s < KCHUNK / 16; ++s) {
        if (s < KCHUNK / 16 - 1) LOAD_STAGE((s + 1) * 16);   // prefetch overlaps compute
#pragma unroll
        for (int kk = 0; kk < 16; ++kk) {
            float4 a0 = *(const float4*)&sA[kk][ty * 8];
            float4 a1 = *(const float4*)&sA[kk][ty * 8 + 4];
            float4 b0 = *(const float4*)&sB[kk][tx * 4];
            float4 b1 = *(const float4*)&sB[kk][64 + tx * 4];
            const float av[8] = {a0.x, a0.y, a0.z, a0.w, a1.x, a1.y, a1.z, a1.w};
#pragma unroll
            for (int i = 0; i < 8; ++i) {
                acc0[i][0] += av[i] * b0.x; acc0[i][1] += av[i] * b0.y;
                acc0[i][2] += av[i] * b0.z; acc0[i][3] += av[i] * b0.w;
                acc1[i][0] += av[i] * b1.x; acc1[i][1] += av[i] * b1.y;
                acc1[i][2] += av[i] * b1.z; acc1[i][3] += av[i] * b1.w;
            }
        }
        __syncthreads();
        if (s < KCHUNK / 16 - 1) {
            STORE_STAGE();
            __syncthreads();
        }
    }

    if (npart == KSPLIT) {
        float* X = w + XP_OFF + ((size_t)zi * KSPLIT + kc) * XSZ;
#pragma unroll
        for (int i = 0; i < 8; ++i) {
            int m = m0 + ty * 8 + i;
            float4 o0; o0.x = acc0[i][0]; o0.y = acc0[i][1]; o0.z = acc0[i][2]; o0.w = acc0[i][3];
            float4 o1; o1.x = acc1[i][0]; o1.y = acc1[i][1]; o1.z = acc1[i][2]; o1.w = acc1[i][3];
            *(float4*)(X + (size_t)m * NPTS + n0 + tx * 4) = o0;
            *(float4*)(X + (size_t)m * NPTS + n0 + 64 + tx * 4) = o1;
        }
    } else {
        float* X = w + XP_OFF + (size_t)zi * XSZ;
#pragma unroll
        for (int i = 0; i < 8; ++i)
#pragma unroll
            for (int j = 0; j < 4; ++j) {
                atomicAdd(X + (size_t)(m0 + ty * 8 + i) * NPTS + n0 + tx * 4 + j, acc0[i][j]);
                atomicAdd(X + (size_t)(m0 + ty * 8 + i) * NPTS + n0 + 64 + tx * 4 + j, acc1[i][j]);
            }
    }
#undef LOAD_STAGE
#undef STORE_STAGE
}

// ---------------- per-slice sigreg (t1 + t2), symmetric-halved --------------
// t1 off-diagonal: sum over circular offsets o=1..128 of S_o; total = 2*s1 - s128.
// grid: (NSLICES, 2); block 256 (one thread per sample point).
__global__ __launch_bounds__(256) void sigreg_kernel(float* __restrict__ w, int npart) {
    __shared__ float ys[2 * NPTS];     // duplicated so reads are base + imm offset
    __shared__ float gsh[K_REF];
    __shared__ float wred[4];
    const int m = blockIdx.x;
    const int zi = blockIdx.y;
    const int tid = threadIdx.x;

    const float* Xb = w + XP_OFF + (size_t)zi * npart * XSZ + (size_t)m * NPTS + tid;
    float xv = 0.f;
    for (int p = 0; p < npart; ++p) xv += Xb[(size_t)p * XSZ];
    if (tid < K_REF) gsh[tid] = w[G_OFF + tid];

    float mu = block_sum_256(xv, wred, tid) * (1.0f / NPTS);
    float dv = xv - mu;
    float ss = block_sum_256(dv * dv, wred, tid);
    float sd = sqrtf(ss * (1.0f / (NPTS - 1))) + 1e-6f;
    float yv = (dv / sd) * SCALE_A;
    ys[tid] = yv;
    ys[tid + NPTS] = yv;
    __syncthreads();

    float s1a = 0.f, s1b = 0.f;
#pragma unroll 8
    for (int o = 1; o <= 128; o += 2) {
        float d0 = yv - ys[tid + o];
        float d1 = yv - ys[tid + o + 1];
        s1a += EXP2(-(d0 * d0));
        s1b += EXP2(-(d1 * d1));
    }
    float d128 = yv - ys[tid + 128];
    float s128 = EXP2(-(d128 * d128));
    float s2 = 0.f;
#pragma unroll
    for (int k = 0; k < K_REF; ++k) {
        float d = yv - gsh[k];
        s2 += EXP2(-(d * d));
    }
    // off-diag = 2*(s1 incl o=128) - s128 ; diagonal N added at tid 0
    float c = (2.0f * (s1a + s1b) - s128) * INV_N2 - s2 * T2_SC;
    if (tid == 0) c += (float)NPTS * INV_N2;
    float tot = block_sum_256(c, wred, tid);
    if (tid == 0) w[SIG_OFF + zi * NSLICES + m] = tot * (0.5f / (float)NSLICES);
}

// ---------------- final: reduce slots + t3 + combine ------------------------
__global__ __launch_bounds__(256) void final_kernel(const float* __restrict__ w,
                                                    float* __restrict__ out) {
    __shared__ float wred[4];
    __shared__ float gsh[K_REF];
    const int tid = threadIdx.x;
    if (tid < K_REF) gsh[tid] = w[G_OFF + tid];
    float sv = 0.f;
    for (int i = tid; i < 2 * NSLICES; i += 256) sv += w[SIG_OFF + i];
    float iv = (tid < 192) ? w[INV_OFF + tid] : 0.f;
    float sig = block_sum_256(sv, wred, tid);
    float inv = block_sum_256(iv, wred, tid);
    // t3 over 289 pairs, parallel (gsh already scaled by SCALE_A)
    float t3p = 0.f;
    for (int idx = tid; idx < K_REF * K_REF; idx += 256) {
        int k = idx / K_REF, l = idx - k * K_REF;
        float d = gsh[k] - gsh[l];
        t3p += EXP2(-(d * d));
    }
    float t3 = block_sum_256(t3p, wred, tid) * (1.0f / ((float)K_REF * (float)K_REF));
    if (tid == 0) {
        out[0] = 25.0f * inv * (1.0f / ((float)NPTS * (float)DIM))
               + 25.0f * (sig + t3);
    }
}

extern "C" void kernel_launch(void* const* d_in, const int* in_sizes, int n_in,
                              void* d_out, int out_size, void* d_ws, size_t ws_size,
                              hipStream_t stream) {
    const float* za = (const float*)d_in[0];
    const float* zb = (const float*)d_in[1];
    const float* slices = (const float*)d_in[2];
    float* out = (float*)d_out;
    float* w = (float*)d_ws;

    const size_t need_full = (size_t)(XP_OFF + 2 * KSPLIT * XSZ) * sizeof(float); // ~16.8 MB
    const int npart = (ws_size >= need_full) ? KSPLIT : 1;

    if (npart == 1)   // fallback only (ws is plenty in this harness; never taken)
        hipMemsetAsync(w + XP_OFF, 0, (size_t)2 * XSZ * sizeof(float), stream);

    inv_kernel<<<192, 256, 0, stream>>>(za, zb, w);
    dim3 pg(2, 8, 2 * KSPLIT);
    proj_kernel<<<pg, 256, 0, stream>>>(za, zb, slices, w, npart);
    dim3 sg(NSLICES, 2);
    sigreg_kernel<<<sg, 256, 0, stream>>>(w, npart);
    final_kernel<<<1, 256, 0, stream>>>(w, out);
}